// Round 11
// baseline (792.390 us; speedup 1.0000x reference)
//
#include <hip/hip_runtime.h>
#include <hip/hip_cooperative_groups.h>
#include <math.h>

#define SE_B     32
#define SE_C     256
#define SE_R     16
#define SE_HW    16384                // floats per plane (128*128)
#define SE_NP    8192                 // planes
#define NBLK     1024                 // 4 blocks/CU, coop co-resident
#define NROUND   8                    // 1024*8 = 8192 planes

typedef float v4f __attribute__((ext_vector_type(4)));
typedef unsigned int u32;
typedef u32 v4u __attribute__((ext_vector_type(4)));

// pack two fp32 -> one u32 of two bf16 (round-half-up); validated R7/R9
__device__ inline u32 pk(float a, float b) {
    u32 ua = __float_as_uint(a), ub = __float_as_uint(b);
    return ((ua + 0x8000u) >> 16) | ((ub + 0x8000u) & 0xffff0000u);
}
__device__ inline float blo(u32 p) { return __uint_as_float(p << 16); }
__device__ inline float bhi(u32 p) { return __uint_as_float(p & 0xffff0000u); }

// ============ pipelined persistent kernel: pool round r ∥ scale round r-1 ============
// Block keeps round r-1's plane bf16-packed in 32 VGPRs. Its batch finished
// pooling a whole round earlier -> the done[] spin is a no-op in steady state.
// x read from HBM exactly once; out written once (NT). ~1.07 GB/call.
__global__ __launch_bounds__(256, 4) void se_pipe2(
    const float* __restrict__ x,
    const float* __restrict__ w1,     // [R, C]
    const float* __restrict__ w2,     // [C, R]
    float* __restrict__ out,
    float* __restrict__ pooled,       // ws: [8192]
    int* __restrict__ done) {         // ws: [32], zeroed per call
    const int t = threadIdx.x;

    __shared__ float wsum[4];
    __shared__ float p_lds[SE_C];
    __shared__ float hpart[SE_R][SE_R + 1];
    __shared__ float h_lds[SE_R];
    __shared__ float g_lds;

    u32 pend[32];                     // previous round's plane, bf16-packed
#pragma unroll
    for (int i = 0; i < 32; ++i) pend[i] = 0;

#pragma unroll 1
    for (int r = 0; r <= NROUND; ++r) {
        u32 cur[32];
        // ---- Phase A: pool plane p_r = r*NBLK + bid (rounds 0..7) ----
        if (r < NROUND) {
            const int p = r * NBLK + blockIdx.x;
            const v4f* xv = reinterpret_cast<const v4f*>(x) + (size_t)p * (SE_HW / 4);
            float s = 0.f;
#pragma unroll
            for (int j = 0; j < 8; ++j) {
                v4f a = __builtin_nontemporal_load(&xv[(2 * j) * 256 + t]);
                v4f b = __builtin_nontemporal_load(&xv[(2 * j + 1) * 256 + t]);
                s += (a.x + a.y) + (a.z + a.w) + (b.x + b.y) + (b.z + b.w);
                cur[4 * j + 0] = pk(a.x, a.y); cur[4 * j + 1] = pk(a.z, a.w);
                cur[4 * j + 2] = pk(b.x, b.y); cur[4 * j + 3] = pk(b.z, b.w);
            }
#pragma unroll
            for (int off = 32; off > 0; off >>= 1) s += __shfl_down(s, off, 64);
            if ((t & 63) == 0) wsum[t >> 6] = s;
            __syncthreads();
            if (t == 0) {
                const float tot = (wsum[0] + wsum[1]) + (wsum[2] + wsum[3]);
                __hip_atomic_store(&pooled[p], tot * (1.0f / SE_HW),
                                   __ATOMIC_RELAXED, __HIP_MEMORY_SCOPE_AGENT);
                __hip_atomic_fetch_add(&done[p >> 8], 1,
                                       __ATOMIC_RELEASE, __HIP_MEMORY_SCOPE_AGENT);
            }
        }
        // ---- Phase B: scale plane p_{r-1} from pend (rounds 1..8) ----
        if (r >= 1) {
            const int p = (r - 1) * NBLK + blockIdx.x;
            const int b = p >> 8, c = p & 255;
            if (t == 0) {               // expected no-op: batch done a round ago
                while (__hip_atomic_load(&done[b], __ATOMIC_ACQUIRE,
                                         __HIP_MEMORY_SCOPE_AGENT) < SE_C)
                    __builtin_amdgcn_s_sleep(2);
            }
            __syncthreads();
            p_lds[t] = __hip_atomic_load(&pooled[b * SE_C + t],
                                         __ATOMIC_RELAXED, __HIP_MEMORY_SCOPE_AGENT);
            __syncthreads();
            {   // h[rr] = relu(sum_c p[c]*w1[rr,c]); C split into 16 segments
                const int rr = t & 15, seg = t >> 4;
                float acc = 0.f;
#pragma unroll
                for (int j = 0; j < 16; ++j) {
                    const int cc = seg * 16 + j;
                    acc = fmaf(p_lds[cc], w1[rr * SE_C + cc], acc);
                }
                hpart[rr][seg] = acc;
            }
            __syncthreads();
            if (t < SE_R) {
                float acc = 0.f;
#pragma unroll
                for (int j = 0; j < 16; ++j) acc += hpart[t][j];
                h_lds[t] = fmaxf(acc, 0.f);
            }
            __syncthreads();
            if (t == 0) {
                float acc = 0.f;
#pragma unroll
                for (int rr = 0; rr < SE_R; ++rr)
                    acc = fmaf(h_lds[rr], w2[c * SE_R + rr], acc);
                g_lds = 1.0f / (1.0f + expf(-acc));
            }
            __syncthreads();
            const float g = g_lds;
            v4f* ov = reinterpret_cast<v4f*>(out) + (size_t)p * (SE_HW / 4);
#pragma unroll
            for (int j = 0; j < 8; ++j) {
                v4f a, bv;
                a.x  = blo(pend[4 * j + 0]) * g;  a.y  = bhi(pend[4 * j + 0]) * g;
                a.z  = blo(pend[4 * j + 1]) * g;  a.w  = bhi(pend[4 * j + 1]) * g;
                bv.x = blo(pend[4 * j + 2]) * g;  bv.y = bhi(pend[4 * j + 2]) * g;
                bv.z = blo(pend[4 * j + 3]) * g;  bv.w = bhi(pend[4 * j + 3]) * g;
                __builtin_nontemporal_store(a,  &ov[(2 * j) * 256 + t]);
                __builtin_nontemporal_store(bv, &ov[(2 * j + 1) * 256 + t]);
            }
        }
        // ---- rotate: pend <- cur (static indices, stays in VGPRs) ----
        if (r < NROUND) {
#pragma unroll
            for (int i = 0; i < 32; ++i) pend[i] = cur[i];
        }
    }
}

// ================= fallback: proven 252 us bf16 3-kernel path =================
__global__ __launch_bounds__(256) void se_pool_pack(const float* __restrict__ x,
                                                    u32* __restrict__ xh,
                                                    float* __restrict__ pooled) {
    const int plane = blockIdx.x;
    const int t = threadIdx.x;
    const v4f* xv = reinterpret_cast<const v4f*>(x) + (size_t)plane * (SE_HW / 4);
    v4u* xh4 = reinterpret_cast<v4u*>(xh) + (size_t)plane * (SE_HW / 8);
    float s = 0.f;
#pragma unroll
    for (int j = 0; j < 8; ++j) {
        v4f a = __builtin_nontemporal_load(&xv[(2 * j) * 256 + t]);
        v4f b = __builtin_nontemporal_load(&xv[(2 * j + 1) * 256 + t]);
        s += (a.x + a.y) + (a.z + a.w) + (b.x + b.y) + (b.z + b.w);
        v4u p;
        p.x = pk(a.x, a.y); p.y = pk(a.z, a.w);
        p.z = pk(b.x, b.y); p.w = pk(b.z, b.w);
        xh4[j * 256 + t] = p;
    }
#pragma unroll
    for (int off = 32; off > 0; off >>= 1) s += __shfl_down(s, off, 64);
    __shared__ float ws[4];
    if ((t & 63) == 0) ws[t >> 6] = s;
    __syncthreads();
    if (t == 0) pooled[plane] = ((ws[0] + ws[1]) + (ws[2] + ws[3])) * (1.0f / SE_HW);
}

__global__ __launch_bounds__(256) void se_gate_kernel(const float* __restrict__ pooled,
                                                      const float* __restrict__ w1,
                                                      const float* __restrict__ w2,
                                                      float* __restrict__ gate) {
    const int b = blockIdx.x;
    const int t = threadIdx.x;
    __shared__ float p[SE_C];
    __shared__ float h[SE_R];
    p[t] = pooled[b * SE_C + t];
    __syncthreads();
    if (t < SE_R) {
        float acc = 0.f;
        for (int c = 0; c < SE_C; ++c) acc = fmaf(p[c], w1[t * SE_C + c], acc);
        h[t] = fmaxf(acc, 0.f);
    }
    __syncthreads();
    float acc = 0.f;
#pragma unroll
    for (int r = 0; r < SE_R; ++r) acc = fmaf(h[r], w2[t * SE_R + r], acc);
    gate[b * SE_C + t] = 1.0f / (1.0f + expf(-acc));
}

__global__ __launch_bounds__(256) void se_scale_bf16(const u32* __restrict__ xh,
                                                     const float* __restrict__ gate,
                                                     float* __restrict__ out) {
    const int plane = SE_NP - 1 - blockIdx.x;
    const int t = threadIdx.x;
    const float g = gate[plane];
    const v4u* xh4 = reinterpret_cast<const v4u*>(xh) + (size_t)plane * (SE_HW / 8);
    v4f* ov = reinterpret_cast<v4f*>(out) + (size_t)plane * (SE_HW / 4);
#pragma unroll
    for (int j = 0; j < 8; ++j) {
        v4u p = xh4[j * 256 + t];
        v4f a, b;
        a.x = blo(p.x); a.y = bhi(p.x); a.z = blo(p.y); a.w = bhi(p.y);
        b.x = blo(p.z); b.y = bhi(p.z); b.z = blo(p.w); b.w = bhi(p.w);
        a *= g; b *= g;
        __builtin_nontemporal_store(a, &ov[(2 * j) * 256 + t]);
        __builtin_nontemporal_store(b, &ov[(2 * j + 1) * 256 + t]);
    }
}

extern "C" void kernel_launch(void* const* d_in, const int* in_sizes, int n_in,
                              void* d_out, int out_size, void* d_ws, size_t ws_size,
                              hipStream_t stream) {
    const float* x  = (const float*)d_in[0];   // [32,256,128,128]
    const float* w1 = (const float*)d_in[1];   // [16,256]
    const float* w2 = (const float*)d_in[2];   // [256,16]
    float* out = (float*)d_out;

    float* pooled  = (float*)d_ws;                                    // 32 KiB
    int*   done    = (int*)((char*)d_ws + SE_NP * sizeof(float));     // 128 B
    float* gatebuf = (float*)((char*)d_ws + SE_NP * sizeof(float) + 256);
    u32*   xh      = (u32*)((char*)d_ws + 2 * SE_NP * sizeof(float) + 256);

    hipMemsetAsync(done, 0, SE_B * sizeof(int), stream);   // counters start at 0

    void* args[] = { (void*)&x, (void*)&w1, (void*)&w2, (void*)&out,
                     (void*)&pooled, (void*)&done };
    hipError_t err = hipLaunchCooperativeKernel((void*)se_pipe2,
                                                dim3(NBLK), dim3(256),
                                                args, 0, stream);
    if (err != hipSuccess) {
        (void)hipGetLastError();               // clear sticky error; proven path
        se_pool_pack<<<SE_NP, 256, 0, stream>>>(x, xh, pooled);
        se_gate_kernel<<<SE_B, 256, 0, stream>>>(pooled, w1, w2, gatebuf);
        se_scale_bf16<<<SE_NP, 256, 0, stream>>>(xh, gatebuf, out);
    }
}

// Round 12
// 730.038 us; speedup vs baseline: 1.0854x; 1.0854x over previous
//
#include <hip/hip_runtime.h>
#include <hip/hip_cooperative_groups.h>
#include <math.h>

#define SE_B     32
#define SE_C     256
#define SE_R     16
#define SE_HW    16384                // floats per plane (128*128)
#define SE_NP    8192                 // planes
#define NBLK     1024                 // 4 blocks/CU co-resident
#define NROUND   4                    // 4 batches per XCD, one per round

typedef float v4f __attribute__((ext_vector_type(4)));
typedef unsigned int u32;
typedef u32 v4u __attribute__((ext_vector_type(4)));

__device__ inline u32 pk(float a, float b) {           // 2x fp32 -> bf16 pair
    u32 ua = __float_as_uint(a), ub = __float_as_uint(b);
    return ((ua + 0x8000u) >> 16) | ((ub + 0x8000u) & 0xffff0000u);
}
__device__ inline float blo(u32 p) { return __uint_as_float(p << 16); }
__device__ inline float bhi(u32 p) { return __uint_as_float(p & 0xffff0000u); }

// ======= persistent kernel, XCD-local sync domains =======
// bid%8 = XCD k (dispatch round-robin heuristic); m = bid/8 in [0,128).
// Round r: XCD k owns batch b = r*8+k; block m pools planes b*256+2m{,+1}
// (plane0 -> 32 VGPRs bf16, plane1 -> 32KB LDS bf16), bumps done[b] (target
// 128 = XCD-local spin), computes gate, scales retained planes. x is read
// from HBM exactly once; out NT-written once. No cross-XCD dependency.
__global__ __launch_bounds__(256, 4) void se_pipe4(
    const float* __restrict__ x,
    const float* __restrict__ w1,     // [R, C]
    const float* __restrict__ w2,     // [C, R]
    float* __restrict__ out,
    float* __restrict__ pooled,       // ws: [8192]
    int* __restrict__ done) {         // ws: [32], zeroed per call
    const int t = threadIdx.x;
    const int k = blockIdx.x & 7;     // XCD (heuristic)
    const int m = blockIdx.x >> 3;    // slot within XCD [0,128)

    __shared__ u32   plane_lds[SE_HW / 2];        // 32 KiB: plane1 as bf16 pairs
    __shared__ float wsum[2][4];
    __shared__ float p_lds[SE_C];
    __shared__ float hpart[SE_R][SE_R + 1];
    __shared__ float h_lds[SE_R];
    __shared__ float g_lds[2];

    v4u* lds4 = reinterpret_cast<v4u*>(plane_lds);

#pragma unroll 1
    for (int r = 0; r < NROUND; ++r) {
        const int b  = r * 8 + k;                 // this round's batch
        const int c0 = 2 * m;                     // channels owned
        const int p0 = b * SE_C + c0;
        const v4f* xv0 = reinterpret_cast<const v4f*>(x) + (size_t)p0 * (SE_HW / 4);
        const v4f* xv1 = xv0 + (SE_HW / 4);

        // ---- pool both planes; retain plane0 in regs, plane1 in LDS ----
        u32 pend[32];
        float s0 = 0.f, s1 = 0.f;
#pragma unroll
        for (int j = 0; j < 8; ++j) {
            v4f a = __builtin_nontemporal_load(&xv0[(2 * j) * 256 + t]);
            v4f bb = __builtin_nontemporal_load(&xv0[(2 * j + 1) * 256 + t]);
            s0 += (a.x + a.y) + (a.z + a.w) + (bb.x + bb.y) + (bb.z + bb.w);
            pend[4 * j + 0] = pk(a.x, a.y);  pend[4 * j + 1] = pk(a.z, a.w);
            pend[4 * j + 2] = pk(bb.x, bb.y); pend[4 * j + 3] = pk(bb.z, bb.w);
            v4f cc = __builtin_nontemporal_load(&xv1[(2 * j) * 256 + t]);
            v4f dd = __builtin_nontemporal_load(&xv1[(2 * j + 1) * 256 + t]);
            s1 += (cc.x + cc.y) + (cc.z + cc.w) + (dd.x + dd.y) + (dd.z + dd.w);
            v4u q;
            q.x = pk(cc.x, cc.y); q.y = pk(cc.z, cc.w);
            q.z = pk(dd.x, dd.y); q.w = pk(dd.z, dd.w);
            lds4[j * 256 + t] = q;                // thread-local slots, no hazard
        }
#pragma unroll
        for (int off = 32; off > 0; off >>= 1) {
            s0 += __shfl_down(s0, off, 64);
            s1 += __shfl_down(s1, off, 64);
        }
        if ((t & 63) == 0) { wsum[0][t >> 6] = s0; wsum[1][t >> 6] = s1; }
        __syncthreads();
        if (t < 2) {
            const float tot = (wsum[t][0] + wsum[t][1]) + (wsum[t][2] + wsum[t][3]);
            __hip_atomic_store(&pooled[p0 + t], tot * (1.0f / SE_HW),
                               __ATOMIC_RELAXED, __HIP_MEMORY_SCOPE_AGENT);
        }
        __syncthreads();                          // both pooled stores issued
        if (t == 0) {
            __hip_atomic_fetch_add(&done[b], 1,
                                   __ATOMIC_RELEASE, __HIP_MEMORY_SCOPE_AGENT);
            // XCD-local spin: wait for this XCD's 128 blocks
            while (__hip_atomic_load(&done[b], __ATOMIC_ACQUIRE,
                                     __HIP_MEMORY_SCOPE_AGENT) < 128)
                __builtin_amdgcn_s_sleep(4);
        }
        __syncthreads();

        // ---- gate MLP for channels c0, c0+1 (agent-scope pooled loads) ----
        p_lds[t] = __hip_atomic_load(&pooled[b * SE_C + t],
                                     __ATOMIC_RELAXED, __HIP_MEMORY_SCOPE_AGENT);
        __syncthreads();
        {   // h[rr] = relu(sum_c p[c]*w1[rr,c]); C split into 16 segments
            const int rr = t & 15, seg = t >> 4;
            float acc = 0.f;
#pragma unroll
            for (int j = 0; j < 16; ++j) {
                const int cc = seg * 16 + j;
                acc = fmaf(p_lds[cc], w1[rr * SE_C + cc], acc);
            }
            hpart[rr][seg] = acc;
        }
        __syncthreads();
        if (t < SE_R) {
            float acc = 0.f;
#pragma unroll
            for (int j = 0; j < 16; ++j) acc += hpart[t][j];
            h_lds[t] = fmaxf(acc, 0.f);
        }
        __syncthreads();
        if (t < 2) {
            float acc = 0.f;
#pragma unroll
            for (int rr = 0; rr < SE_R; ++rr)
                acc = fmaf(h_lds[rr], w2[(c0 + t) * SE_R + rr], acc);
            g_lds[t] = 1.0f / (1.0f + expf(-acc));
        }
        __syncthreads();
        const float g0 = g_lds[0], g1 = g_lds[1];

        // ---- scale: plane0 from regs, plane1 from LDS; NT stores ----
        v4f* ov0 = reinterpret_cast<v4f*>(out) + (size_t)p0 * (SE_HW / 4);
        v4f* ov1 = ov0 + (SE_HW / 4);
#pragma unroll
        for (int j = 0; j < 8; ++j) {
            v4f a, bb;
            a.x  = blo(pend[4 * j + 0]) * g0;  a.y  = bhi(pend[4 * j + 0]) * g0;
            a.z  = blo(pend[4 * j + 1]) * g0;  a.w  = bhi(pend[4 * j + 1]) * g0;
            bb.x = blo(pend[4 * j + 2]) * g0;  bb.y = bhi(pend[4 * j + 2]) * g0;
            bb.z = blo(pend[4 * j + 3]) * g0;  bb.w = bhi(pend[4 * j + 3]) * g0;
            __builtin_nontemporal_store(a,  &ov0[(2 * j) * 256 + t]);
            __builtin_nontemporal_store(bb, &ov0[(2 * j + 1) * 256 + t]);
            v4u q = lds4[j * 256 + t];
            v4f cc, dd;
            cc.x = blo(q.x) * g1; cc.y = bhi(q.x) * g1;
            cc.z = blo(q.y) * g1; cc.w = bhi(q.y) * g1;
            dd.x = blo(q.z) * g1; dd.y = bhi(q.z) * g1;
            dd.z = blo(q.w) * g1; dd.w = bhi(q.w) * g1;
            __builtin_nontemporal_store(cc, &ov1[(2 * j) * 256 + t]);
            __builtin_nontemporal_store(dd, &ov1[(2 * j + 1) * 256 + t]);
        }
        __syncthreads();                          // LDS safe to overwrite next round
    }
}

// ================= fallback: proven 252 us bf16 3-kernel path =================
__global__ __launch_bounds__(256) void se_pool_pack(const float* __restrict__ x,
                                                    u32* __restrict__ xh,
                                                    float* __restrict__ pooled) {
    const int plane = blockIdx.x;
    const int t = threadIdx.x;
    const v4f* xv = reinterpret_cast<const v4f*>(x) + (size_t)plane * (SE_HW / 4);
    v4u* xh4 = reinterpret_cast<v4u*>(xh) + (size_t)plane * (SE_HW / 8);
    float s = 0.f;
#pragma unroll
    for (int j = 0; j < 8; ++j) {
        v4f a = __builtin_nontemporal_load(&xv[(2 * j) * 256 + t]);
        v4f b = __builtin_nontemporal_load(&xv[(2 * j + 1) * 256 + t]);
        s += (a.x + a.y) + (a.z + a.w) + (b.x + b.y) + (b.z + b.w);
        v4u p;
        p.x = pk(a.x, a.y); p.y = pk(a.z, a.w);
        p.z = pk(b.x, b.y); p.w = pk(b.z, b.w);
        xh4[j * 256 + t] = p;
    }
#pragma unroll
    for (int off = 32; off > 0; off >>= 1) s += __shfl_down(s, off, 64);
    __shared__ float ws[4];
    if ((t & 63) == 0) ws[t >> 6] = s;
    __syncthreads();
    if (t == 0) pooled[plane] = ((ws[0] + ws[1]) + (ws[2] + ws[3])) * (1.0f / SE_HW);
}

__global__ __launch_bounds__(256) void se_gate_kernel(const float* __restrict__ pooled,
                                                      const float* __restrict__ w1,
                                                      const float* __restrict__ w2,
                                                      float* __restrict__ gate) {
    const int b = blockIdx.x;
    const int t = threadIdx.x;
    __shared__ float p[SE_C];
    __shared__ float h[SE_R];
    p[t] = pooled[b * SE_C + t];
    __syncthreads();
    if (t < SE_R) {
        float acc = 0.f;
        for (int c = 0; c < SE_C; ++c) acc = fmaf(p[c], w1[t * SE_C + c], acc);
        h[t] = fmaxf(acc, 0.f);
    }
    __syncthreads();
    float acc = 0.f;
#pragma unroll
    for (int r = 0; r < SE_R; ++r) acc = fmaf(h[r], w2[t * SE_R + r], acc);
    gate[b * SE_C + t] = 1.0f / (1.0f + expf(-acc));
}

__global__ __launch_bounds__(256) void se_scale_bf16(const u32* __restrict__ xh,
                                                     const float* __restrict__ gate,
                                                     float* __restrict__ out) {
    const int plane = SE_NP - 1 - blockIdx.x;
    const int t = threadIdx.x;
    const float g = gate[plane];
    const v4u* xh4 = reinterpret_cast<const v4u*>(xh) + (size_t)plane * (SE_HW / 8);
    v4f* ov = reinterpret_cast<v4f*>(out) + (size_t)plane * (SE_HW / 4);
#pragma unroll
    for (int j = 0; j < 8; ++j) {
        v4u p = xh4[j * 256 + t];
        v4f a, b;
        a.x = blo(p.x); a.y = bhi(p.x); a.z = blo(p.y); a.w = bhi(p.y);
        b.x = blo(p.z); b.y = bhi(p.z); b.z = blo(p.w); b.w = bhi(p.w);
        a *= g; b *= g;
        __builtin_nontemporal_store(a, &ov[(2 * j) * 256 + t]);
        __builtin_nontemporal_store(b, &ov[(2 * j + 1) * 256 + t]);
    }
}

extern "C" void kernel_launch(void* const* d_in, const int* in_sizes, int n_in,
                              void* d_out, int out_size, void* d_ws, size_t ws_size,
                              hipStream_t stream) {
    const float* x  = (const float*)d_in[0];   // [32,256,128,128]
    const float* w1 = (const float*)d_in[1];   // [16,256]
    const float* w2 = (const float*)d_in[2];   // [256,16]
    float* out = (float*)d_out;

    float* pooled  = (float*)d_ws;                                    // 32 KiB
    int*   done    = (int*)((char*)d_ws + SE_NP * sizeof(float));     // 128 B
    float* gatebuf = (float*)((char*)d_ws + SE_NP * sizeof(float) + 256);
    u32*   xh      = (u32*)((char*)d_ws + 2 * SE_NP * sizeof(float) + 256);

    hipMemsetAsync(done, 0, SE_B * sizeof(int), stream);   // counters start at 0

    void* args[] = { (void*)&x, (void*)&w1, (void*)&w2, (void*)&out,
                     (void*)&pooled, (void*)&done };
    hipError_t err = hipLaunchCooperativeKernel((void*)se_pipe4,
                                                dim3(NBLK), dim3(256),
                                                args, 0, stream);
    if (err != hipSuccess) {
        (void)hipGetLastError();               // clear sticky error; proven path
        se_pool_pack<<<SE_NP, 256, 0, stream>>>(x, xh, pooled);
        se_gate_kernel<<<SE_B, 256, 0, stream>>>(pooled, w1, w2, gatebuf);
        se_scale_bf16<<<SE_NP, 256, 0, stream>>>(xh, gatebuf, out);
    }
}

// Round 13
// 411.175 us; speedup vs baseline: 1.9271x; 1.7755x over previous
//
#include <hip/hip_runtime.h>
#include <hip/hip_cooperative_groups.h>
#include <math.h>

#define SE_B     32
#define SE_C     256
#define SE_R     16
#define SE_HW    16384                // floats per plane (128*128)
#define SE_NP    8192                 // planes
#define NBLK     1024                 // 4 blocks/CU co-resident
#define NROUND   4                    // 4 batches per XCD, one per round

typedef float v4f __attribute__((ext_vector_type(4)));
typedef unsigned int u32;
typedef u32 v4u __attribute__((ext_vector_type(4)));

__device__ inline u32 pk(float a, float b) {           // 2x fp32 -> bf16 pair
    u32 ua = __float_as_uint(a), ub = __float_as_uint(b);
    return ((ua + 0x8000u) >> 16) | ((ub + 0x8000u) & 0xffff0000u);
}
__device__ inline float blo(u32 p) { return __uint_as_float(p << 16); }
__device__ inline float bhi(u32 p) { return __uint_as_float(p & 0xffff0000u); }

// ======= persistent kernel, XCD-local sync domains, RELAXED-ONLY sync =======
// All cross-block communication uses relaxed agent-scope atomics (sc1 ->
// executed at the MALL coherence point, NO L2 writeback/invalidate). Ordering:
// pooled stores are drained by the vmcnt(0) the compiler emits before
// __syncthreads(); the done-add follows in program order; a spin observing
// done==128 therefore implies all pooled sc1-stores reached the MALL, and our
// pooled sc1-loads read the MALL directly. No acquire/release anywhere.
__global__ __launch_bounds__(256, 4) void se_pipe5(
    const float* __restrict__ x,
    const float* __restrict__ w1,     // [R, C]
    const float* __restrict__ w2,     // [C, R]
    float* __restrict__ out,
    float* __restrict__ pooled,       // ws: [8192]
    int* __restrict__ done) {         // ws: [32], zeroed per call
    const int t = threadIdx.x;
    const int k = blockIdx.x & 7;     // XCD (dispatch round-robin heuristic)
    const int m = blockIdx.x >> 3;    // slot within XCD [0,128)

    __shared__ u32   plane_lds[SE_HW / 2];        // 32 KiB: plane1 as bf16 pairs
    __shared__ float wsum[2][4];
    __shared__ float p_lds[SE_C];
    __shared__ float hpart[SE_R][SE_R + 1];
    __shared__ float h_lds[SE_R];
    __shared__ float g_lds[2];

    v4u* lds4 = reinterpret_cast<v4u*>(plane_lds);

#pragma unroll 1
    for (int r = 0; r < NROUND; ++r) {
        const int b  = r * 8 + k;                 // this round's batch
        const int c0 = 2 * m;                     // channels owned
        const int p0 = b * SE_C + c0;
        const v4f* xv0 = reinterpret_cast<const v4f*>(x) + (size_t)p0 * (SE_HW / 4);
        const v4f* xv1 = xv0 + (SE_HW / 4);

        // ---- pool both planes; retain plane0 in regs, plane1 in LDS ----
        u32 pend[32];
        float s0 = 0.f, s1 = 0.f;
#pragma unroll
        for (int j = 0; j < 8; ++j) {
            v4f a = __builtin_nontemporal_load(&xv0[(2 * j) * 256 + t]);
            v4f bb = __builtin_nontemporal_load(&xv0[(2 * j + 1) * 256 + t]);
            s0 += (a.x + a.y) + (a.z + a.w) + (bb.x + bb.y) + (bb.z + bb.w);
            pend[4 * j + 0] = pk(a.x, a.y);  pend[4 * j + 1] = pk(a.z, a.w);
            pend[4 * j + 2] = pk(bb.x, bb.y); pend[4 * j + 3] = pk(bb.z, bb.w);
            v4f cc = __builtin_nontemporal_load(&xv1[(2 * j) * 256 + t]);
            v4f dd = __builtin_nontemporal_load(&xv1[(2 * j + 1) * 256 + t]);
            s1 += (cc.x + cc.y) + (cc.z + cc.w) + (dd.x + dd.y) + (dd.z + dd.w);
            v4u q;
            q.x = pk(cc.x, cc.y); q.y = pk(cc.z, cc.w);
            q.z = pk(dd.x, dd.y); q.w = pk(dd.z, dd.w);
            lds4[j * 256 + t] = q;                // thread-local slots, no hazard
        }
#pragma unroll
        for (int off = 32; off > 0; off >>= 1) {
            s0 += __shfl_down(s0, off, 64);
            s1 += __shfl_down(s1, off, 64);
        }
        if ((t & 63) == 0) { wsum[0][t >> 6] = s0; wsum[1][t >> 6] = s1; }
        __syncthreads();
        if (t < 2) {
            const float tot = (wsum[t][0] + wsum[t][1]) + (wsum[t][2] + wsum[t][3]);
            __hip_atomic_store(&pooled[p0 + t], tot * (1.0f / SE_HW),
                               __ATOMIC_RELAXED, __HIP_MEMORY_SCOPE_AGENT);
        }
        __syncthreads();                          // vmcnt(0): pooled stores at MALL
        if (t == 0) {
            __hip_atomic_fetch_add(&done[b], 1,   // RELAXED: no L2 writeback
                                   __ATOMIC_RELAXED, __HIP_MEMORY_SCOPE_AGENT);
            // XCD-local spin, RELAXED sc1 polls (no L2 invalidate per poll)
            while (__hip_atomic_load(&done[b], __ATOMIC_RELAXED,
                                     __HIP_MEMORY_SCOPE_AGENT) < 128)
                __builtin_amdgcn_s_sleep(4);
        }
        __syncthreads();

        // ---- gate MLP for channels c0, c0+1 (relaxed sc1 pooled loads) ----
        p_lds[t] = __hip_atomic_load(&pooled[b * SE_C + t],
                                     __ATOMIC_RELAXED, __HIP_MEMORY_SCOPE_AGENT);
        __syncthreads();
        {   // h[rr] = relu(sum_c p[c]*w1[rr,c]); C split into 16 segments
            const int rr = t & 15, seg = t >> 4;
            float acc = 0.f;
#pragma unroll
            for (int j = 0; j < 16; ++j) {
                const int cc = seg * 16 + j;
                acc = fmaf(p_lds[cc], w1[rr * SE_C + cc], acc);
            }
            hpart[rr][seg] = acc;
        }
        __syncthreads();
        if (t < SE_R) {
            float acc = 0.f;
#pragma unroll
            for (int j = 0; j < 16; ++j) acc += hpart[t][j];
            h_lds[t] = fmaxf(acc, 0.f);
        }
        __syncthreads();
        if (t < 2) {
            float acc = 0.f;
#pragma unroll
            for (int rr = 0; rr < SE_R; ++rr)
                acc = fmaf(h_lds[rr], w2[(c0 + t) * SE_R + rr], acc);
            g_lds[t] = 1.0f / (1.0f + expf(-acc));
        }
        __syncthreads();
        const float g0 = g_lds[0], g1 = g_lds[1];

        // ---- scale: plane0 from regs, plane1 from LDS; NT stores ----
        v4f* ov0 = reinterpret_cast<v4f*>(out) + (size_t)p0 * (SE_HW / 4);
        v4f* ov1 = ov0 + (SE_HW / 4);
#pragma unroll
        for (int j = 0; j < 8; ++j) {
            v4f a, bb;
            a.x  = blo(pend[4 * j + 0]) * g0;  a.y  = bhi(pend[4 * j + 0]) * g0;
            a.z  = blo(pend[4 * j + 1]) * g0;  a.w  = bhi(pend[4 * j + 1]) * g0;
            bb.x = blo(pend[4 * j + 2]) * g0;  bb.y = bhi(pend[4 * j + 2]) * g0;
            bb.z = blo(pend[4 * j + 3]) * g0;  bb.w = bhi(pend[4 * j + 3]) * g0;
            __builtin_nontemporal_store(a,  &ov0[(2 * j) * 256 + t]);
            __builtin_nontemporal_store(bb, &ov0[(2 * j + 1) * 256 + t]);
            v4u q = lds4[j * 256 + t];
            v4f cc, dd;
            cc.x = blo(q.x) * g1; cc.y = bhi(q.x) * g1;
            cc.z = blo(q.y) * g1; cc.w = bhi(q.y) * g1;
            dd.x = blo(q.z) * g1; dd.y = bhi(q.z) * g1;
            dd.z = blo(q.w) * g1; dd.w = bhi(q.w) * g1;
            __builtin_nontemporal_store(cc, &ov1[(2 * j) * 256 + t]);
            __builtin_nontemporal_store(dd, &ov1[(2 * j + 1) * 256 + t]);
        }
        __syncthreads();                          // LDS safe to overwrite next round
    }
}

// ================= fallback: proven 252 us bf16 3-kernel path =================
__global__ __launch_bounds__(256) void se_pool_pack(const float* __restrict__ x,
                                                    u32* __restrict__ xh,
                                                    float* __restrict__ pooled) {
    const int plane = blockIdx.x;
    const int t = threadIdx.x;
    const v4f* xv = reinterpret_cast<const v4f*>(x) + (size_t)plane * (SE_HW / 4);
    v4u* xh4 = reinterpret_cast<v4u*>(xh) + (size_t)plane * (SE_HW / 8);
    float s = 0.f;
#pragma unroll
    for (int j = 0; j < 8; ++j) {
        v4f a = __builtin_nontemporal_load(&xv[(2 * j) * 256 + t]);
        v4f b = __builtin_nontemporal_load(&xv[(2 * j + 1) * 256 + t]);
        s += (a.x + a.y) + (a.z + a.w) + (b.x + b.y) + (b.z + b.w);
        v4u p;
        p.x = pk(a.x, a.y); p.y = pk(a.z, a.w);
        p.z = pk(b.x, b.y); p.w = pk(b.z, b.w);
        xh4[j * 256 + t] = p;
    }
#pragma unroll
    for (int off = 32; off > 0; off >>= 1) s += __shfl_down(s, off, 64);
    __shared__ float ws[4];
    if ((t & 63) == 0) ws[t >> 6] = s;
    __syncthreads();
    if (t == 0) pooled[plane] = ((ws[0] + ws[1]) + (ws[2] + ws[3])) * (1.0f / SE_HW);
}

__global__ __launch_bounds__(256) void se_gate_kernel(const float* __restrict__ pooled,
                                                      const float* __restrict__ w1,
                                                      const float* __restrict__ w2,
                                                      float* __restrict__ gate) {
    const int b = blockIdx.x;
    const int t = threadIdx.x;
    __shared__ float p[SE_C];
    __shared__ float h[SE_R];
    p[t] = pooled[b * SE_C + t];
    __syncthreads();
    if (t < SE_R) {
        float acc = 0.f;
        for (int c = 0; c < SE_C; ++c) acc = fmaf(p[c], w1[t * SE_C + c], acc);
        h[t] = fmaxf(acc, 0.f);
    }
    __syncthreads();
    float acc = 0.f;
#pragma unroll
    for (int r = 0; r < SE_R; ++r) acc = fmaf(h[r], w2[t * SE_R + r], acc);
    gate[b * SE_C + t] = 1.0f / (1.0f + expf(-acc));
}

__global__ __launch_bounds__(256) void se_scale_bf16(const u32* __restrict__ xh,
                                                     const float* __restrict__ gate,
                                                     float* __restrict__ out) {
    const int plane = SE_NP - 1 - blockIdx.x;
    const int t = threadIdx.x;
    const float g = gate[plane];
    const v4u* xh4 = reinterpret_cast<const v4u*>(xh) + (size_t)plane * (SE_HW / 8);
    v4f* ov = reinterpret_cast<v4f*>(out) + (size_t)plane * (SE_HW / 4);
#pragma unroll
    for (int j = 0; j < 8; ++j) {
        v4u p = xh4[j * 256 + t];
        v4f a, b;
        a.x = blo(p.x); a.y = bhi(p.x); a.z = blo(p.y); a.w = bhi(p.y);
        b.x = blo(p.z); b.y = bhi(p.z); b.z = blo(p.w); b.w = bhi(p.w);
        a *= g; b *= g;
        __builtin_nontemporal_store(a, &ov[(2 * j) * 256 + t]);
        __builtin_nontemporal_store(b, &ov[(2 * j + 1) * 256 + t]);
    }
}

extern "C" void kernel_launch(void* const* d_in, const int* in_sizes, int n_in,
                              void* d_out, int out_size, void* d_ws, size_t ws_size,
                              hipStream_t stream) {
    const float* x  = (const float*)d_in[0];   // [32,256,128,128]
    const float* w1 = (const float*)d_in[1];   // [16,256]
    const float* w2 = (const float*)d_in[2];   // [256,16]
    float* out = (float*)d_out;

    float* pooled  = (float*)d_ws;                                    // 32 KiB
    int*   done    = (int*)((char*)d_ws + SE_NP * sizeof(float));     // 128 B
    float* gatebuf = (float*)((char*)d_ws + SE_NP * sizeof(float) + 256);
    u32*   xh      = (u32*)((char*)d_ws + 2 * SE_NP * sizeof(float) + 256);

    hipMemsetAsync(done, 0, SE_B * sizeof(int), stream);   // counters start at 0

    void* args[] = { (void*)&x, (void*)&w1, (void*)&w2, (void*)&out,
                     (void*)&pooled, (void*)&done };
    hipError_t err = hipLaunchCooperativeKernel((void*)se_pipe5,
                                                dim3(NBLK), dim3(256),
                                                args, 0, stream);
    if (err != hipSuccess) {
        (void)hipGetLastError();               // clear sticky error; proven path
        se_pool_pack<<<SE_NP, 256, 0, stream>>>(x, xh, pooled);
        se_gate_kernel<<<SE_B, 256, 0, stream>>>(pooled, w1, w2, gatebuf);
        se_scale_bf16<<<SE_NP, 256, 0, stream>>>(xh, gatebuf, out);
    }
}

// Round 14
// 288.518 us; speedup vs baseline: 2.7464x; 1.4251x over previous
//
#include <hip/hip_runtime.h>
#include <hip/hip_cooperative_groups.h>
#include <math.h>

#define SE_B     32
#define SE_C     256
#define SE_R     16
#define SE_HW    16384                // floats per plane (128*128)
#define SE_NP    8192                 // planes
#define NBLK     1024                 // 4 blocks/CU co-resident
#define NROUND   4                    // 4 batches per XCD, one per round
#define DSTRIDE  32                   // ints: 128 B per done-counter line

typedef float v4f __attribute__((ext_vector_type(4)));
typedef unsigned int u32;
typedef u32 v4u __attribute__((ext_vector_type(4)));

__device__ inline u32 pk(float a, float b) {           // 2x fp32 -> bf16 pair
    u32 ua = __float_as_uint(a), ub = __float_as_uint(b);
    return ((ua + 0x8000u) >> 16) | ((ub + 0x8000u) & 0xffff0000u);
}
__device__ inline float blo(u32 p) { return __uint_as_float(p << 16); }
__device__ inline float bhi(u32 p) { return __uint_as_float(p & 0xffff0000u); }

// ======= persistent kernel: XCD-local domains, relaxed sync, PADDED counters =======
// R13 + two changes: (1) done[b] padded to one 128-B line each -> no false
// sharing between the 8 concurrent batch domains, adds/polls to different
// batches no longer serialize on one MALL line; (2) backoff polling.
__global__ __launch_bounds__(256, 4) void se_pipe6(
    const float* __restrict__ x,
    const float* __restrict__ w1,     // [R, C]
    const float* __restrict__ w2,     // [C, R]
    float* __restrict__ out,
    float* __restrict__ pooled,       // ws: [8192]
    int* __restrict__ done) {         // ws: [32*DSTRIDE], zeroed per call
    const int t = threadIdx.x;
    const int k = blockIdx.x & 7;     // XCD (dispatch round-robin heuristic)
    const int m = blockIdx.x >> 3;    // slot within XCD [0,128)

    __shared__ u32   plane_lds[SE_HW / 2];        // 32 KiB: plane1 as bf16 pairs
    __shared__ float wsum[2][4];
    __shared__ float p_lds[SE_C];
    __shared__ float hpart[SE_R][SE_R + 1];
    __shared__ float h_lds[SE_R];
    __shared__ float g_lds[2];

    v4u* lds4 = reinterpret_cast<v4u*>(plane_lds);

#pragma unroll 1
    for (int r = 0; r < NROUND; ++r) {
        const int b  = r * 8 + k;                 // this round's batch
        const int c0 = 2 * m;                     // channels owned
        const int p0 = b * SE_C + c0;
        const v4f* xv0 = reinterpret_cast<const v4f*>(x) + (size_t)p0 * (SE_HW / 4);
        const v4f* xv1 = xv0 + (SE_HW / 4);

        // ---- pool both planes; retain plane0 in regs, plane1 in LDS ----
        u32 pend[32];
        float s0 = 0.f, s1 = 0.f;
#pragma unroll
        for (int j = 0; j < 8; ++j) {
            v4f a = __builtin_nontemporal_load(&xv0[(2 * j) * 256 + t]);
            v4f bb = __builtin_nontemporal_load(&xv0[(2 * j + 1) * 256 + t]);
            s0 += (a.x + a.y) + (a.z + a.w) + (bb.x + bb.y) + (bb.z + bb.w);
            pend[4 * j + 0] = pk(a.x, a.y);  pend[4 * j + 1] = pk(a.z, a.w);
            pend[4 * j + 2] = pk(bb.x, bb.y); pend[4 * j + 3] = pk(bb.z, bb.w);
            v4f cc = __builtin_nontemporal_load(&xv1[(2 * j) * 256 + t]);
            v4f dd = __builtin_nontemporal_load(&xv1[(2 * j + 1) * 256 + t]);
            s1 += (cc.x + cc.y) + (cc.z + cc.w) + (dd.x + dd.y) + (dd.z + dd.w);
            v4u q;
            q.x = pk(cc.x, cc.y); q.y = pk(cc.z, cc.w);
            q.z = pk(dd.x, dd.y); q.w = pk(dd.z, dd.w);
            lds4[j * 256 + t] = q;                // thread-local slots, no hazard
        }
#pragma unroll
        for (int off = 32; off > 0; off >>= 1) {
            s0 += __shfl_down(s0, off, 64);
            s1 += __shfl_down(s1, off, 64);
        }
        if ((t & 63) == 0) { wsum[0][t >> 6] = s0; wsum[1][t >> 6] = s1; }
        __syncthreads();
        if (t < 2) {
            const float tot = (wsum[t][0] + wsum[t][1]) + (wsum[t][2] + wsum[t][3]);
            __hip_atomic_store(&pooled[p0 + t], tot * (1.0f / SE_HW),
                               __ATOMIC_RELAXED, __HIP_MEMORY_SCOPE_AGENT);
        }
        __syncthreads();                          // vmcnt(0): pooled stores at MALL
        if (t == 0) {
            int* dctr = &done[b * DSTRIDE];       // private 128-B line per batch
            __hip_atomic_fetch_add(dctr, 1,       // RELAXED: no L2 writeback
                                   __ATOMIC_RELAXED, __HIP_MEMORY_SCOPE_AGENT);
            // backoff spin: immediate check, then long sleeps (few polls total)
            while (__hip_atomic_load(dctr, __ATOMIC_RELAXED,
                                     __HIP_MEMORY_SCOPE_AGENT) < 128)
                __builtin_amdgcn_s_sleep(32);
        }
        __syncthreads();

        // ---- gate MLP for channels c0, c0+1 (relaxed sc1 pooled loads) ----
        p_lds[t] = __hip_atomic_load(&pooled[b * SE_C + t],
                                     __ATOMIC_RELAXED, __HIP_MEMORY_SCOPE_AGENT);
        __syncthreads();
        {   // h[rr] = relu(sum_c p[c]*w1[rr,c]); C split into 16 segments
            const int rr = t & 15, seg = t >> 4;
            float acc = 0.f;
#pragma unroll
            for (int j = 0; j < 16; ++j) {
                const int cc = seg * 16 + j;
                acc = fmaf(p_lds[cc], w1[rr * SE_C + cc], acc);
            }
            hpart[rr][seg] = acc;
        }
        __syncthreads();
        if (t < SE_R) {
            float acc = 0.f;
#pragma unroll
            for (int j = 0; j < 16; ++j) acc += hpart[t][j];
            h_lds[t] = fmaxf(acc, 0.f);
        }
        __syncthreads();
        if (t < 2) {
            float acc = 0.f;
#pragma unroll
            for (int rr = 0; rr < SE_R; ++rr)
                acc = fmaf(h_lds[rr], w2[(c0 + t) * SE_R + rr], acc);
            g_lds[t] = 1.0f / (1.0f + expf(-acc));
        }
        __syncthreads();
        const float g0 = g_lds[0], g1 = g_lds[1];

        // ---- scale: plane0 from regs, plane1 from LDS; NT stores ----
        v4f* ov0 = reinterpret_cast<v4f*>(out) + (size_t)p0 * (SE_HW / 4);
        v4f* ov1 = ov0 + (SE_HW / 4);
#pragma unroll
        for (int j = 0; j < 8; ++j) {
            v4f a, bb;
            a.x  = blo(pend[4 * j + 0]) * g0;  a.y  = bhi(pend[4 * j + 0]) * g0;
            a.z  = blo(pend[4 * j + 1]) * g0;  a.w  = bhi(pend[4 * j + 1]) * g0;
            bb.x = blo(pend[4 * j + 2]) * g0;  bb.y = bhi(pend[4 * j + 2]) * g0;
            bb.z = blo(pend[4 * j + 3]) * g0;  bb.w = bhi(pend[4 * j + 3]) * g0;
            __builtin_nontemporal_store(a,  &ov0[(2 * j) * 256 + t]);
            __builtin_nontemporal_store(bb, &ov0[(2 * j + 1) * 256 + t]);
            v4u q = lds4[j * 256 + t];
            v4f cc, dd;
            cc.x = blo(q.x) * g1; cc.y = bhi(q.x) * g1;
            cc.z = blo(q.y) * g1; cc.w = bhi(q.y) * g1;
            dd.x = blo(q.z) * g1; dd.y = bhi(q.z) * g1;
            dd.z = blo(q.w) * g1; dd.w = bhi(q.w) * g1;
            __builtin_nontemporal_store(cc, &ov1[(2 * j) * 256 + t]);
            __builtin_nontemporal_store(dd, &ov1[(2 * j + 1) * 256 + t]);
        }
        __syncthreads();                          // LDS safe to overwrite next round
    }
}

// ================= fallback: proven 252 us bf16 3-kernel path =================
__global__ __launch_bounds__(256) void se_pool_pack(const float* __restrict__ x,
                                                    u32* __restrict__ xh,
                                                    float* __restrict__ pooled) {
    const int plane = blockIdx.x;
    const int t = threadIdx.x;
    const v4f* xv = reinterpret_cast<const v4f*>(x) + (size_t)plane * (SE_HW / 4);
    v4u* xh4 = reinterpret_cast<v4u*>(xh) + (size_t)plane * (SE_HW / 8);
    float s = 0.f;
#pragma unroll
    for (int j = 0; j < 8; ++j) {
        v4f a = __builtin_nontemporal_load(&xv[(2 * j) * 256 + t]);
        v4f b = __builtin_nontemporal_load(&xv[(2 * j + 1) * 256 + t]);
        s += (a.x + a.y) + (a.z + a.w) + (b.x + b.y) + (b.z + b.w);
        v4u p;
        p.x = pk(a.x, a.y); p.y = pk(a.z, a.w);
        p.z = pk(b.x, b.y); p.w = pk(b.z, b.w);
        xh4[j * 256 + t] = p;
    }
#pragma unroll
    for (int off = 32; off > 0; off >>= 1) s += __shfl_down(s, off, 64);
    __shared__ float ws[4];
    if ((t & 63) == 0) ws[t >> 6] = s;
    __syncthreads();
    if (t == 0) pooled[plane] = ((ws[0] + ws[1]) + (ws[2] + ws[3])) * (1.0f / SE_HW);
}

__global__ __launch_bounds__(256) void se_gate_kernel(const float* __restrict__ pooled,
                                                      const float* __restrict__ w1,
                                                      const float* __restrict__ w2,
                                                      float* __restrict__ gate) {
    const int b = blockIdx.x;
    const int t = threadIdx.x;
    __shared__ float p[SE_C];
    __shared__ float h[SE_R];
    p[t] = pooled[b * SE_C + t];
    __syncthreads();
    if (t < SE_R) {
        float acc = 0.f;
        for (int c = 0; c < SE_C; ++c) acc = fmaf(p[c], w1[t * SE_C + c], acc);
        h[t] = fmaxf(acc, 0.f);
    }
    __syncthreads();
    float acc = 0.f;
#pragma unroll
    for (int r = 0; r < SE_R; ++r) acc = fmaf(h[r], w2[t * SE_R + r], acc);
    gate[b * SE_C + t] = 1.0f / (1.0f + expf(-acc));
}

__global__ __launch_bounds__(256) void se_scale_bf16(const u32* __restrict__ xh,
                                                     const float* __restrict__ gate,
                                                     float* __restrict__ out) {
    const int plane = SE_NP - 1 - blockIdx.x;
    const int t = threadIdx.x;
    const float g = gate[plane];
    const v4u* xh4 = reinterpret_cast<const v4u*>(xh) + (size_t)plane * (SE_HW / 8);
    v4f* ov = reinterpret_cast<v4f*>(out) + (size_t)plane * (SE_HW / 4);
#pragma unroll
    for (int j = 0; j < 8; ++j) {
        v4u p = xh4[j * 256 + t];
        v4f a, b;
        a.x = blo(p.x); a.y = bhi(p.x); a.z = blo(p.y); a.w = bhi(p.y);
        b.x = blo(p.z); b.y = bhi(p.z); b.z = blo(p.w); b.w = bhi(p.w);
        a *= g; b *= g;
        __builtin_nontemporal_store(a, &ov[(2 * j) * 256 + t]);
        __builtin_nontemporal_store(b, &ov[(2 * j + 1) * 256 + t]);
    }
}

extern "C" void kernel_launch(void* const* d_in, const int* in_sizes, int n_in,
                              void* d_out, int out_size, void* d_ws, size_t ws_size,
                              hipStream_t stream) {
    const float* x  = (const float*)d_in[0];   // [32,256,128,128]
    const float* w1 = (const float*)d_in[1];   // [16,256]
    const float* w2 = (const float*)d_in[2];   // [256,16]
    float* out = (float*)d_out;

    float* pooled  = (float*)d_ws;                                    // 32 KiB
    int*   done    = (int*)((char*)d_ws + SE_NP * sizeof(float));     // 4 KiB padded
    float* gatebuf = (float*)((char*)d_ws + SE_NP * sizeof(float) + SE_B * DSTRIDE * 4);
    u32*   xh      = (u32*)((char*)d_ws + 2 * SE_NP * sizeof(float) + SE_B * DSTRIDE * 4);

    hipMemsetAsync(done, 0, SE_B * DSTRIDE * sizeof(int), stream);

    void* args[] = { (void*)&x, (void*)&w1, (void*)&w2, (void*)&out,
                     (void*)&pooled, (void*)&done };
    hipError_t err = hipLaunchCooperativeKernel((void*)se_pipe6,
                                                dim3(NBLK), dim3(256),
                                                args, 0, stream);
    if (err != hipSuccess) {
        (void)hipGetLastError();               // clear sticky error; proven path
        se_pool_pack<<<SE_NP, 256, 0, stream>>>(x, xh, pooled);
        se_gate_kernel<<<SE_B, 256, 0, stream>>>(pooled, w1, w2, gatebuf);
        se_scale_bf16<<<SE_NP, 256, 0, stream>>>(xh, gatebuf, out);
    }
}

// Round 15
// 243.960 us; speedup vs baseline: 3.2480x; 1.1826x over previous
//
#include <hip/hip_runtime.h>
#include <math.h>

#define SE_B   32
#define SE_C   256
#define SE_R   16
#define SE_HW  16384                 // floats per plane (128*128)
#define SE_NP  (SE_B * SE_C)         // 8192 planes

typedef float v4f __attribute__((ext_vector_type(4)));
typedef unsigned int u32;
typedef u32 v4u __attribute__((ext_vector_type(4)));

// pack two fp32 -> one u32 of two bf16 (round-half-up); validated R7 (absmax .0156)
__device__ inline u32 pk(float a, float b) {
    u32 ua = __float_as_uint(a), ub = __float_as_uint(b);
    return ((ua + 0x8000u) >> 16) | ((ub + 0x8000u) & 0xffff0000u);
}
__device__ inline float blo(u32 p) { return __uint_as_float(p << 16); }
__device__ inline float bhi(u32 p) { return __uint_as_float(p & 0xffff0000u); }

// ---- K1: pool + bf16-pack. One block per plane, ascending.
// Reads x (537 MB) NT, writes xh (268 MB). ~805 MB fabric traffic. ----
__global__ __launch_bounds__(256) void se_pool_pack(const float* __restrict__ x,
                                                    u32* __restrict__ xh,
                                                    float* __restrict__ pooled) {
    const int plane = blockIdx.x;
    const int t = threadIdx.x;
    const v4f* xv = reinterpret_cast<const v4f*>(x) + (size_t)plane * (SE_HW / 4);
    v4u* xh4 = reinterpret_cast<v4u*>(xh) + (size_t)plane * (SE_HW / 8);
    float s = 0.f;
#pragma unroll
    for (int j = 0; j < 8; ++j) {
        v4f a = __builtin_nontemporal_load(&xv[(2 * j) * 256 + t]);
        v4f b = __builtin_nontemporal_load(&xv[(2 * j + 1) * 256 + t]);
        s += (a.x + a.y) + (a.z + a.w) + (b.x + b.y) + (b.z + b.w);
        v4u p;
        p.x = pk(a.x, a.y); p.y = pk(a.z, a.w);
        p.z = pk(b.x, b.y); p.w = pk(b.z, b.w);
        xh4[j * 256 + t] = p;
    }
#pragma unroll
    for (int off = 32; off > 0; off >>= 1) s += __shfl_down(s, off, 64);
    __shared__ float ws[4];
    if ((t & 63) == 0) ws[t >> 6] = s;
    __syncthreads();
    if (t == 0) pooled[plane] = ((ws[0] + ws[1]) + (ws[2] + ws[3])) * (1.0f / SE_HW);
}

// ---- K2: fused gate + scale. One block per plane, DESCENDING order.
// Block computes its own gate (R8-validated cooperative MLP, ~0.3us), then
// scales its plane from the bf16 copy: reads xh (268 MB), NT-writes out
// (537 MB). No separate gate kernel / launch gap. ----
__global__ __launch_bounds__(256) void se_scale_fused(const u32* __restrict__ xh,
                                                      const float* __restrict__ pooled,
                                                      const float* __restrict__ w1,   // [R,C]
                                                      const float* __restrict__ w2,   // [C,R]
                                                      float* __restrict__ out) {
    const int plane = SE_NP - 1 - blockIdx.x;     // descending sweep
    const int b = plane >> 8;                     // batch
    const int c = plane & 255;                    // channel
    const int t = threadIdx.x;

    __shared__ float p_lds[SE_C];
    __shared__ float hpart[SE_R][SE_R + 1];
    __shared__ float h_lds[SE_R];
    __shared__ float g_lds;

    p_lds[t] = pooled[b * SE_C + t];
    __syncthreads();
    {   // h[r] = relu(sum_c p[c]*w1[r,c]); C split into 16 segments
        const int r = t & 15, seg = t >> 4;
        float acc = 0.f;
#pragma unroll
        for (int j = 0; j < 16; ++j) {
            const int cc = seg * 16 + j;
            acc = fmaf(p_lds[cc], w1[r * SE_C + cc], acc);
        }
        hpart[r][seg] = acc;
    }
    __syncthreads();
    if (t < SE_R) {
        float acc = 0.f;
#pragma unroll
        for (int j = 0; j < 16; ++j) acc += hpart[t][j];
        h_lds[t] = fmaxf(acc, 0.f);
    }
    __syncthreads();
    if (t == 0) {
        float acc = 0.f;
#pragma unroll
        for (int r = 0; r < SE_R; ++r) acc = fmaf(h_lds[r], w2[c * SE_R + r], acc);
        g_lds = 1.0f / (1.0f + expf(-acc));
    }
    __syncthreads();
    const float g = g_lds;

    const v4u* xh4 = reinterpret_cast<const v4u*>(xh) + (size_t)plane * (SE_HW / 8);
    v4f* ov = reinterpret_cast<v4f*>(out) + (size_t)plane * (SE_HW / 4);
#pragma unroll
    for (int j = 0; j < 8; ++j) {
        v4u p = xh4[j * 256 + t];
        v4f a, bb;
        a.x  = blo(p.x) * g; a.y  = bhi(p.x) * g;
        a.z  = blo(p.y) * g; a.w  = bhi(p.y) * g;
        bb.x = blo(p.z) * g; bb.y = bhi(p.z) * g;
        bb.z = blo(p.w) * g; bb.w = bhi(p.w) * g;
        __builtin_nontemporal_store(a,  &ov[(2 * j) * 256 + t]);
        __builtin_nontemporal_store(bb, &ov[(2 * j + 1) * 256 + t]);
    }
}

// ================= fallback (fp32 two-pass) if ws is too small =================
__global__ __launch_bounds__(256) void se_pool_kernel(const float* __restrict__ x,
                                                      float* __restrict__ pooled) {
    const int bc = blockIdx.x;
    const v4f* xv = reinterpret_cast<const v4f*>(x + (size_t)bc * SE_HW);
    const int t = threadIdx.x;
    float s = 0.f;
#pragma unroll
    for (int k = 0; k < 16; ++k) {
        v4f v = xv[t + k * 256];
        s += (v.x + v.y) + (v.z + v.w);
    }
#pragma unroll
    for (int off = 32; off > 0; off >>= 1) s += __shfl_down(s, off, 64);
    __shared__ float ws[4];
    if ((t & 63) == 0) ws[t >> 6] = s;
    __syncthreads();
    if (t == 0) pooled[bc] = ((ws[0] + ws[1]) + (ws[2] + ws[3])) * (1.0f / SE_HW);
}

__global__ __launch_bounds__(256) void se_scale_fused_f32(const float* __restrict__ x,
                                                          const float* __restrict__ pooled,
                                                          const float* __restrict__ w1,
                                                          const float* __restrict__ w2,
                                                          float* __restrict__ out) {
    const int plane = SE_NP - 1 - blockIdx.x;
    const int b = plane >> 8;
    const int c = plane & 255;
    const int t = threadIdx.x;

    __shared__ float p_lds[SE_C];
    __shared__ float hpart[SE_R][SE_R + 1];
    __shared__ float h_lds[SE_R];
    __shared__ float g_lds;

    p_lds[t] = pooled[b * SE_C + t];
    __syncthreads();
    {
        const int r = t & 15, seg = t >> 4;
        float acc = 0.f;
#pragma unroll
        for (int j = 0; j < 16; ++j) {
            const int cc = seg * 16 + j;
            acc = fmaf(p_lds[cc], w1[r * SE_C + cc], acc);
        }
        hpart[r][seg] = acc;
    }
    __syncthreads();
    if (t < SE_R) {
        float acc = 0.f;
#pragma unroll
        for (int j = 0; j < 16; ++j) acc += hpart[t][j];
        h_lds[t] = fmaxf(acc, 0.f);
    }
    __syncthreads();
    if (t == 0) {
        float acc = 0.f;
#pragma unroll
        for (int r = 0; r < SE_R; ++r) acc = fmaf(h_lds[r], w2[c * SE_R + r], acc);
        g_lds = 1.0f / (1.0f + expf(-acc));
    }
    __syncthreads();
    const float g = g_lds;

    const v4f* xv = reinterpret_cast<const v4f*>(x) + (size_t)plane * (SE_HW / 4);
    v4f* ov = reinterpret_cast<v4f*>(out) + (size_t)plane * (SE_HW / 4);
#pragma unroll
    for (int k = 0; k < 16; ++k) {
        v4f v = xv[k * 256 + t];
        v *= g;
        __builtin_nontemporal_store(v, &ov[k * 256 + t]);
    }
}

extern "C" void kernel_launch(void* const* d_in, const int* in_sizes, int n_in,
                              void* d_out, int out_size, void* d_ws, size_t ws_size,
                              hipStream_t stream) {
    const float* x  = (const float*)d_in[0];   // [32,256,128,128]
    const float* w1 = (const float*)d_in[1];   // [16,256]
    const float* w2 = (const float*)d_in[2];   // [256,16]
    float* out = (float*)d_out;

    float* pooled = (float*)d_ws;                                   // 32 KiB
    u32*   xh     = (u32*)((char*)d_ws + SE_NP * sizeof(float));    // 268 MB
    const size_t need = SE_NP * sizeof(float)
                      + (size_t)SE_NP * SE_HW * 2 /*bf16 bytes*/;

    if (ws_size >= need) {
        se_pool_pack<<<SE_NP, 256, 0, stream>>>(x, xh, pooled);
        se_scale_fused<<<SE_NP, 256, 0, stream>>>(xh, pooled, w1, w2, out);
    } else {
        se_pool_kernel<<<SE_NP, 256, 0, stream>>>(x, pooled);
        se_scale_fused_f32<<<SE_NP, 256, 0, stream>>>(x, pooled, w1, w2, out);
    }
}